// Round 9
// baseline (82.308 us; speedup 1.0000x reference)
//
#include <hip/hip_runtime.h>
#include <float.h>

#define N_NODES 200000
#define D 256
#define HID 512
#define OUTD 2
#define NG 512

__device__ __forceinline__ float4 fmax4(float4 a, float4 b) {
    return make_float4(fmaxf(a.x, b.x), fmaxf(a.y, b.y), fmaxf(a.z, b.z), fmaxf(a.w, b.w));
}
__device__ __forceinline__ float4 shflx4(float4 v, int mask) {
    return make_float4(__shfl_xor(v.x, mask), __shfl_xor(v.y, mask),
                       __shfl_xor(v.z, mask), __shfl_xor(v.w, mask));
}

// ---------------------------------------------------------------------------
// Kernel 1: segment boundaries from sorted batch (proven).
// ---------------------------------------------------------------------------
__global__ void k_bounds(const int* __restrict__ batch, int* __restrict__ row_start, int n) {
    int i = blockIdx.x * blockDim.x + threadIdx.x;
    if (i >= n) return;
    int b  = batch[i];
    int bp = (i == 0) ? -1 : batch[i - 1];
    for (int g = bp + 1; g <= b; ++g) row_start[g] = i;
    if (i == n - 1) {
        for (int g = b + 1; g <= NG; ++g) row_start[g] = n;
    }
}

// ---------------------------------------------------------------------------
// Kernel 2: FUSED pool + 3-layer MLP. One block per graph (512 blocks,
// 2/CU). Pool result stays in LDS; MLP phase of one block overlaps other
// blocks' pool phases (intra-CU TLP). Weights are L2-resident per XCD.
// Pool: lane owns 64 B contiguous; wave = 4 consecutive rows (4 KB dense);
// tail rows clamp to r1-1 (same graph -> duplicate fmax no-op).
// MLP: thread t owns output cols {2t, 2t+1}; activations broadcast from LDS;
// weights float2-coalesced, unroll 4 -> 16 loads in flight per thread.
// ---------------------------------------------------------------------------
__global__ __launch_bounds__(256) void k_fused(const float* __restrict__ x,
                                               const int* __restrict__ rs,
                                               const float* __restrict__ W1,
                                               const float* __restrict__ b1,
                                               const float* __restrict__ W2,
                                               const float* __restrict__ b2,
                                               const float* __restrict__ W3,
                                               const float* __restrict__ b3,
                                               float* __restrict__ out) {
    const int g    = blockIdx.x;
    const int t    = threadIdx.x;
    const int lane = t & 63;
    const int wave = t >> 6;

    __shared__ float gr[D];             // pooled row
    __shared__ float h1s[HID];
    __shared__ float h2s[HID];
    __shared__ float red[4][16][16];
    __shared__ float fin[4][2];

    // ---------------- pool graph g ----------------
    const int r0 = rs[g];
    const int r1 = rs[g + 1];
    const int len = r1 - r0;

    const float4 NEUT = make_float4(-FLT_MAX, -FLT_MAX, -FLT_MAX, -FLT_MAX);
    float4 m0 = NEUT, m1 = NEUT, m2 = NEUT, m3 = NEUT;

    if (len > 0) {
        const int rlast = r1 - 1;
        const int sub = lane >> 4;            // row within wave's 4-row group
        const int cq  = (lane & 15) * 16;     // col start (floats)
        const int iters = (len + 15) >> 4;    // 16 rows per block-iteration
        for (int i = 0; i < iters; ++i) {
            int row = r0 + i * 16 + wave * 4 + sub;
            row = min(row, rlast);
            const float* p = x + (size_t)row * D + cq;
            float4 v0 = *reinterpret_cast<const float4*>(p);
            float4 v1 = *reinterpret_cast<const float4*>(p + 4);
            float4 v2 = *reinterpret_cast<const float4*>(p + 8);
            float4 v3 = *reinterpret_cast<const float4*>(p + 12);
            m0 = fmax4(m0, v0); m1 = fmax4(m1, v1);
            m2 = fmax4(m2, v2); m3 = fmax4(m3, v3);
        }
    }

    m0 = fmax4(m0, shflx4(m0, 16)); m0 = fmax4(m0, shflx4(m0, 32));
    m1 = fmax4(m1, shflx4(m1, 16)); m1 = fmax4(m1, shflx4(m1, 32));
    m2 = fmax4(m2, shflx4(m2, 16)); m2 = fmax4(m2, shflx4(m2, 32));
    m3 = fmax4(m3, shflx4(m3, 16)); m3 = fmax4(m3, shflx4(m3, 32));

    if (lane < 16) {
        *reinterpret_cast<float4*>(&red[wave][lane][0])  = m0;
        *reinterpret_cast<float4*>(&red[wave][lane][4])  = m1;
        *reinterpret_cast<float4*>(&red[wave][lane][8])  = m2;
        *reinterpret_cast<float4*>(&red[wave][lane][12]) = m3;
    }
    __syncthreads();
    {
        const int cg = t >> 4, e = t & 15;    // col = t
        float o = fmaxf(fmaxf(red[0][cg][e], red[1][cg][e]),
                        fmaxf(red[2][cg][e], red[3][cg][e]));
        gr[t] = (len > 0) ? o : 0.f;          // empty graph -> zeros (matches ref)
    }
    __syncthreads();

    // ---------------- layer 1: gr[256] @ W1[256,512] + b1, relu ----------------
    {
        float a0 = 0.f, a1 = 0.f;
        const float* w = W1 + 2 * t;
#pragma unroll 4
        for (int k = 0; k < D; k += 4) {
            float4 xa = *reinterpret_cast<const float4*>(&gr[k]);
            float2 w0 = *reinterpret_cast<const float2*>(w + (size_t)(k)     * HID);
            float2 w1 = *reinterpret_cast<const float2*>(w + (size_t)(k + 1) * HID);
            float2 w2 = *reinterpret_cast<const float2*>(w + (size_t)(k + 2) * HID);
            float2 w3 = *reinterpret_cast<const float2*>(w + (size_t)(k + 3) * HID);
            a0 += xa.x * w0.x + xa.y * w1.x + xa.z * w2.x + xa.w * w3.x;
            a1 += xa.x * w0.y + xa.y * w1.y + xa.z * w2.y + xa.w * w3.y;
        }
        float2 bb = *reinterpret_cast<const float2*>(b1 + 2 * t);
        h1s[2 * t]     = fmaxf(a0 + bb.x, 0.f);
        h1s[2 * t + 1] = fmaxf(a1 + bb.y, 0.f);
    }
    __syncthreads();

    // ---------------- layer 2: h1[512] @ W2[512,512] + b2, relu ----------------
    {
        float a0 = 0.f, a1 = 0.f;
        const float* w = W2 + 2 * t;
#pragma unroll 4
        for (int k = 0; k < HID; k += 4) {
            float4 xa = *reinterpret_cast<const float4*>(&h1s[k]);
            float2 w0 = *reinterpret_cast<const float2*>(w + (size_t)(k)     * HID);
            float2 w1 = *reinterpret_cast<const float2*>(w + (size_t)(k + 1) * HID);
            float2 w2 = *reinterpret_cast<const float2*>(w + (size_t)(k + 2) * HID);
            float2 w3 = *reinterpret_cast<const float2*>(w + (size_t)(k + 3) * HID);
            a0 += xa.x * w0.x + xa.y * w1.x + xa.z * w2.x + xa.w * w3.x;
            a1 += xa.x * w0.y + xa.y * w1.y + xa.z * w2.y + xa.w * w3.y;
        }
        float2 bb = *reinterpret_cast<const float2*>(b2 + 2 * t);
        h2s[2 * t]     = fmaxf(a0 + bb.x, 0.f);
        h2s[2 * t + 1] = fmaxf(a1 + bb.y, 0.f);
    }
    __syncthreads();

    // ---------------- layer 3: h2[512] @ W3[512,2] + b3 ----------------
    {
        float4 w = *reinterpret_cast<const float4*>(W3 + 4 * t);  // W3[2t][:], W3[2t+1][:]
        float2 h = *reinterpret_cast<const float2*>(&h2s[2 * t]);
        float p0 = h.x * w.x + h.y * w.z;
        float p1 = h.x * w.y + h.y * w.w;
#pragma unroll
        for (int off = 32; off; off >>= 1) {
            p0 += __shfl_xor(p0, off);
            p1 += __shfl_xor(p1, off);
        }
        if (lane == 0) { fin[wave][0] = p0; fin[wave][1] = p1; }
        __syncthreads();
        if (t < 2) {
            float s = fin[0][t] + fin[1][t] + fin[2][t] + fin[3][t];
            out[(size_t)g * OUTD + t] = s + b3[t];
        }
    }
}

// ---------------------------------------------------------------------------
extern "C" void kernel_launch(void* const* d_in, const int* in_sizes, int n_in,
                              void* d_out, int out_size, void* d_ws, size_t ws_size,
                              hipStream_t stream) {
    const float* x     = (const float*)d_in[0];
    const int*   batch = (const int*)d_in[1];
    const float* W1    = (const float*)d_in[2];
    const float* b1    = (const float*)d_in[3];
    const float* W2    = (const float*)d_in[4];
    const float* b2    = (const float*)d_in[5];
    const float* W3    = (const float*)d_in[6];
    const float* b3    = (const float*)d_in[7];
    float* out = (float*)d_out;

    int* row_start = (int*)d_ws;   // NG+1 ints

    k_bounds<<<(N_NODES + 255) / 256, 256, 0, stream>>>(batch, row_start, N_NODES);
    k_fused<<<NG, 256, 0, stream>>>(x, row_start, W1, b1, W2, b2, W3, b3, out);
}

// Round 10
// 70.475 us; speedup vs baseline: 1.1679x; 1.1679x over previous
//
#include <hip/hip_runtime.h>
#include <float.h>

#define N_NODES 200000
#define D 256
#define HID 512
#define OUTD 2
#define NG 512
#define SLICES 4                       // slice-blocks per graph

__device__ __forceinline__ float4 fmax4(float4 a, float4 b) {
    return make_float4(fmaxf(a.x, b.x), fmaxf(a.y, b.y), fmaxf(a.z, b.z), fmaxf(a.w, b.w));
}
__device__ __forceinline__ float4 shflx4(float4 v, int mask) {
    return make_float4(__shfl_xor(v.x, mask), __shfl_xor(v.y, mask),
                       __shfl_xor(v.z, mask), __shfl_xor(v.w, mask));
}

// ---------------------------------------------------------------------------
// Kernel 1: segment boundaries from sorted batch (proven).
// ---------------------------------------------------------------------------
__global__ void k_bounds(const int* __restrict__ batch, int* __restrict__ row_start, int n) {
    int i = blockIdx.x * blockDim.x + threadIdx.x;
    if (i >= n) return;
    int b  = batch[i];
    int bp = (i == 0) ? -1 : batch[i - 1];
    for (int g = bp + 1; g <= b; ++g) row_start[g] = i;
    if (i == n - 1) {
        for (int g = b + 1; g <= NG; ++g) row_start[g] = n;
    }
}

// ---------------------------------------------------------------------------
// Kernel 2: sliced segment-max pool. Block b handles slice q = b&3 of graph
// g = b>>2 (2048 blocks, 32 waves/CU = full occupancy). Slice rows are a
// contiguous quarter of the graph. R8 dense-front layout: lane owns 64 B
// contiguous, wave = 4 consecutive rows; unroll-2 dual accumulators -> 8
// independent float4 loads in flight per lane. Partial max -> scr[b][256];
// empty slice -> -FLT_MAX sentinel (consumed by gemm1's fused reduce).
// ---------------------------------------------------------------------------
__global__ __launch_bounds__(256) void k_pool(const float* __restrict__ x,
                                              const int* __restrict__ rs,
                                              float* __restrict__ scr) {
    const int blk  = blockIdx.x;
    const int g    = blk >> 2;
    const int q    = blk & 3;
    const int t    = threadIdx.x;
    const int lane = t & 63;
    const int wave = t >> 6;

    const int r0g = rs[g];
    const int r1g = rs[g + 1];
    const int len = r1g - r0g;
    const int c   = (len + SLICES - 1) >> 2;        // slice width (ceil)
    const int s0  = r0g + q * c;
    const int s1  = min(s0 + c, r1g);
    const int slen = s1 - s0;

    const float4 NEUT = make_float4(-FLT_MAX, -FLT_MAX, -FLT_MAX, -FLT_MAX);
    float4 mA0 = NEUT, mA1 = NEUT, mA2 = NEUT, mA3 = NEUT;
    float4 mB0 = NEUT, mB1 = NEUT, mB2 = NEUT, mB3 = NEUT;

    if (slen > 0) {
        const int rlast = s1 - 1;
        const int sub = lane >> 4;                  // row within wave's 4-row group
        const int cq  = (lane & 15) * 16;           // col start (floats)
        const int iters = (slen + 31) >> 5;         // 32 rows per outer iteration
        for (int i = 0; i < iters; ++i) {
            int rowA = s0 + i * 32 + wave * 4 + sub;
            int rowB = rowA + 16;
            rowA = min(rowA, rlast);
            rowB = min(rowB, rlast);
            const float* pA = x + (size_t)rowA * D + cq;
            const float* pB = x + (size_t)rowB * D + cq;
            float4 a0 = *reinterpret_cast<const float4*>(pA);
            float4 a1 = *reinterpret_cast<const float4*>(pA + 4);
            float4 a2 = *reinterpret_cast<const float4*>(pA + 8);
            float4 a3 = *reinterpret_cast<const float4*>(pA + 12);
            float4 b0 = *reinterpret_cast<const float4*>(pB);
            float4 b1 = *reinterpret_cast<const float4*>(pB + 4);
            float4 b2 = *reinterpret_cast<const float4*>(pB + 8);
            float4 b3 = *reinterpret_cast<const float4*>(pB + 12);
            mA0 = fmax4(mA0, a0); mA1 = fmax4(mA1, a1);
            mA2 = fmax4(mA2, a2); mA3 = fmax4(mA3, a3);
            mB0 = fmax4(mB0, b0); mB1 = fmax4(mB1, b1);
            mB2 = fmax4(mB2, b2); mB3 = fmax4(mB3, b3);
        }
    }
    float4 m0 = fmax4(mA0, mB0), m1 = fmax4(mA1, mB1);
    float4 m2 = fmax4(mA2, mB2), m3 = fmax4(mA3, mB3);

    // combine lanes sharing the same col range (l, l^16, l^32, l^48)
    m0 = fmax4(m0, shflx4(m0, 16)); m0 = fmax4(m0, shflx4(m0, 32));
    m1 = fmax4(m1, shflx4(m1, 16)); m1 = fmax4(m1, shflx4(m1, 32));
    m2 = fmax4(m2, shflx4(m2, 16)); m2 = fmax4(m2, shflx4(m2, 32));
    m3 = fmax4(m3, shflx4(m3, 16)); m3 = fmax4(m3, shflx4(m3, 32));

    __shared__ float red[4][16][16];                // [wave][colgrp][elem]
    if (lane < 16) {
        *reinterpret_cast<float4*>(&red[wave][lane][0])  = m0;
        *reinterpret_cast<float4*>(&red[wave][lane][4])  = m1;
        *reinterpret_cast<float4*>(&red[wave][lane][8])  = m2;
        *reinterpret_cast<float4*>(&red[wave][lane][12]) = m3;
    }
    __syncthreads();
    {
        const int cg = t >> 4, e = t & 15;          // col = t
        float o = fmaxf(fmaxf(red[0][cg][e], red[1][cg][e]),
                        fmaxf(red[2][cg][e], red[3][cg][e]));
        scr[(size_t)blk * D + t] = o;               // NEUT if slice empty
    }
}

// ---------------------------------------------------------------------------
// Kernel 3a: layer-1 GEMM with fused slice-reduce A-load.
// A[g][k] = len(g)>0 ? max_q scr[g*4+q][k] : 0.  Otherwise verbatim R1 GEMM.
// ---------------------------------------------------------------------------
__global__ __launch_bounds__(256) void k_gemm1(const float* __restrict__ scr,
                                               const int* __restrict__ rs,
                                               const float* __restrict__ B,
                                               const float* __restrict__ bias,
                                               float* __restrict__ C, int N) {
    __shared__ float As[32][33];
    __shared__ float Bs[32][33];
    const int t  = threadIdx.x;
    const int bm = blockIdx.y * 32;
    const int bn = blockIdx.x * 32;
    const int lr = t >> 3;
    const int lc = (t & 7) << 2;
    const int tx = t & 15;
    const int ty = t >> 4;

    const int grow = bm + lr;                       // graph id for A loads
    const bool nonempty = rs[grow + 1] > rs[grow];
    const float* srow = scr + (size_t)grow * 4 * D;

    float acc00 = 0.f, acc01 = 0.f, acc10 = 0.f, acc11 = 0.f;

    for (int k0 = 0; k0 < D; k0 += 32) {
        float4 a0 = *reinterpret_cast<const float4*>(srow + 0 * D + k0 + lc);
        float4 a1 = *reinterpret_cast<const float4*>(srow + 1 * D + k0 + lc);
        float4 a2 = *reinterpret_cast<const float4*>(srow + 2 * D + k0 + lc);
        float4 a3 = *reinterpret_cast<const float4*>(srow + 3 * D + k0 + lc);
        float4 av = fmax4(fmax4(a0, a1), fmax4(a2, a3));
        if (!nonempty) av = make_float4(0.f, 0.f, 0.f, 0.f);
        float4 bv = *reinterpret_cast<const float4*>(B + (size_t)(k0 + lr) * N + bn + lc);
        __syncthreads();
        As[lr][lc] = av.x; As[lr][lc + 1] = av.y; As[lr][lc + 2] = av.z; As[lr][lc + 3] = av.w;
        Bs[lr][lc] = bv.x; Bs[lr][lc + 1] = bv.y; Bs[lr][lc + 2] = bv.z; Bs[lr][lc + 3] = bv.w;
        __syncthreads();
#pragma unroll
        for (int kk = 0; kk < 32; ++kk) {
            float a0s = As[ty * 2][kk], a1s = As[ty * 2 + 1][kk];
            float b0s = Bs[kk][tx * 2], b1s = Bs[kk][tx * 2 + 1];
            acc00 += a0s * b0s; acc01 += a0s * b1s;
            acc10 += a1s * b0s; acc11 += a1s * b1s;
        }
    }

    const int r = bm + ty * 2, cc = bn + tx * 2;
    float bc0 = bias[cc], bc1 = bias[cc + 1];
    float v00 = fmaxf(acc00 + bc0, 0.f), v01 = fmaxf(acc01 + bc1, 0.f);
    float v10 = fmaxf(acc10 + bc0, 0.f), v11 = fmaxf(acc11 + bc1, 0.f);
    C[(size_t)r * N + cc]           = v00;
    C[(size_t)r * N + cc + 1]       = v01;
    C[(size_t)(r + 1) * N + cc]     = v10;
    C[(size_t)(r + 1) * N + cc + 1] = v11;
}

// ---------------------------------------------------------------------------
// Kernel 3b: layer-2 GEMM (verbatim R1).
// ---------------------------------------------------------------------------
__global__ __launch_bounds__(256) void k_gemm2(const float* __restrict__ A,
                                               const float* __restrict__ B,
                                               const float* __restrict__ bias,
                                               float* __restrict__ C, int N) {
    __shared__ float As[32][33];
    __shared__ float Bs[32][33];
    const int t  = threadIdx.x;
    const int bm = blockIdx.y * 32;
    const int bn = blockIdx.x * 32;
    const int lr = t >> 3;
    const int lc = (t & 7) << 2;
    const int tx = t & 15;
    const int ty = t >> 4;
    float acc00 = 0.f, acc01 = 0.f, acc10 = 0.f, acc11 = 0.f;

    for (int k0 = 0; k0 < HID; k0 += 32) {
        float4 av = *reinterpret_cast<const float4*>(A + (size_t)(bm + lr) * HID + k0 + lc);
        float4 bv = *reinterpret_cast<const float4*>(B + (size_t)(k0 + lr) * N + bn + lc);
        __syncthreads();
        As[lr][lc] = av.x; As[lr][lc + 1] = av.y; As[lr][lc + 2] = av.z; As[lr][lc + 3] = av.w;
        Bs[lr][lc] = bv.x; Bs[lr][lc + 1] = bv.y; Bs[lr][lc + 2] = bv.z; Bs[lr][lc + 3] = bv.w;
        __syncthreads();
#pragma unroll
        for (int kk = 0; kk < 32; ++kk) {
            float a0 = As[ty * 2][kk], a1 = As[ty * 2 + 1][kk];
            float b0 = Bs[kk][tx * 2], b1 = Bs[kk][tx * 2 + 1];
            acc00 += a0 * b0; acc01 += a0 * b1;
            acc10 += a1 * b0; acc11 += a1 * b1;
        }
    }

    const int r = bm + ty * 2, c = bn + tx * 2;
    float bc0 = bias[c], bc1 = bias[c + 1];
    float v00 = fmaxf(acc00 + bc0, 0.f), v01 = fmaxf(acc01 + bc1, 0.f);
    float v10 = fmaxf(acc10 + bc0, 0.f), v11 = fmaxf(acc11 + bc1, 0.f);
    C[(size_t)r * N + c]           = v00;
    C[(size_t)r * N + c + 1]       = v01;
    C[(size_t)(r + 1) * N + c]     = v10;
    C[(size_t)(r + 1) * N + c + 1] = v11;
}

// ---------------------------------------------------------------------------
// Kernel 4: final [512,HID] @ [HID,2] + b3 (verbatim R1).
// ---------------------------------------------------------------------------
__global__ __launch_bounds__(256) void k_fc3(const float* __restrict__ h,
                                             const float* __restrict__ W,
                                             const float* __restrict__ b,
                                             float* __restrict__ out) {
    const int wave = threadIdx.x >> 6;
    const int lane = threadIdx.x & 63;
    const int e = blockIdx.x * 4 + wave;
    const int row = e >> 1, col = e & 1;
    float s = 0.f;
#pragma unroll
    for (int k = lane; k < HID; k += 64)
        s += h[(size_t)row * HID + k] * W[(size_t)k * OUTD + col];
#pragma unroll
    for (int off = 32; off; off >>= 1) s += __shfl_xor(s, off);
    if (lane == 0) out[e] = s + b[col];
}

// ---------------------------------------------------------------------------
extern "C" void kernel_launch(void* const* d_in, const int* in_sizes, int n_in,
                              void* d_out, int out_size, void* d_ws, size_t ws_size,
                              hipStream_t stream) {
    const float* x     = (const float*)d_in[0];
    const int*   batch = (const int*)d_in[1];
    const float* W1    = (const float*)d_in[2];
    const float* b1    = (const float*)d_in[3];
    const float* W2    = (const float*)d_in[4];
    const float* b2    = (const float*)d_in[5];
    const float* W3    = (const float*)d_in[6];
    const float* b3    = (const float*)d_in[7];
    float* out = (float*)d_out;

    char* ws = (char*)d_ws;
    int*   row_start = (int*)ws;                                     // 513 ints
    float* scr = (float*)(ws + 4096);                                // 2048*256*4 = 2 MB
    float* h1  = (float*)(ws + 4096 + 2 * 1024 * 1024);              // 1 MB
    float* h2  = (float*)(ws + 4096 + 3 * 1024 * 1024);              // 1 MB

    k_bounds<<<(N_NODES + 255) / 256, 256, 0, stream>>>(batch, row_start, N_NODES);
    k_pool<<<NG * SLICES, 256, 0, stream>>>(x, row_start, scr);
    k_gemm1<<<dim3(HID / 32, NG / 32), 256, 0, stream>>>(scr, row_start, W1, b1, h1, HID);
    k_gemm2<<<dim3(HID / 32, NG / 32), 256, 0, stream>>>(h1, W2, b2, h2, HID);
    k_fc3<<<NG * OUTD / 4, 256, 0, stream>>>(h2, W3, b3, out);
}